// Round 3
// baseline (117.168 us; speedup 1.0000x reference)
//
#include <hip/hip_runtime.h>
#include <hip/hip_bf16.h>

#define N 8192
#define D 256
// sim = dot/0.5 = 2*dot; rows normalized -> fixed shift 2.0 replaces row-max
// (log-sum-exp shift invariance). Diagonal + positive-count handled in finalize.
// Symmetric: only tiles with col_tile_start >= row_block_start are computed;
// off-diag tiles feed both row-sums (regs) and col-sums (shfl+atomic).

typedef __attribute__((ext_vector_type(8))) short bf16x8;
typedef __attribute__((ext_vector_type(4))) float f32x4;

#define RB 128                 // rows per row-block (block = 2 waves x 64 rows)
#define CTW 32                 // cols per tile
#define NRB (N / RB)           // 64
#define NTILES 8320            // sum_{rb<64} (256 - 4*rb) = 2*64*65
#define GRID 1024
#define TPB 128

#define K1 2.8853900817779268f   // 2*log2(e)
#define K2 (-2.8853900817779268f)

__device__ inline unsigned short f2bf(float x) {
    __hip_bfloat16 h = __float2bfloat16(x);
    return *reinterpret_cast<unsigned short*>(&h);
}

__device__ inline float fast_exp2(float t) {
#if __has_builtin(__builtin_amdgcn_exp2f)
    return __builtin_amdgcn_exp2f(t);
#else
    return __expf(t * 0.69314718056f);
#endif
}

__device__ inline int cumtiles(int rb) { return 2 * rb * (129 - rb); }

__device__ inline void decode_tile(int k, int& rb, int& ct) {
    float f = 64.5f - sqrtf(4160.25f - 0.5f * (float)k);
    rb = (int)f;
    if (rb < 0) rb = 0;
    if (rb > 63) rb = 63;
    while (rb < 63 && cumtiles(rb + 1) <= k) ++rb;
    while (rb > 0 && cumtiles(rb) > k) --rb;
    ct = rb * 4 + (k - cumtiles(rb));
}

// ---------------- kernel 1: fp32 -> bf16 convert + zero accumulators ----------------
__global__ void convert_kernel(const float4* __restrict__ E4, ushort4* __restrict__ Ebf4,
                               float* __restrict__ Z, float* __restrict__ P) {
    int i = blockIdx.x * blockDim.x + threadIdx.x;
    if (i < (N * D) / 4) {
        float4 v = E4[i];
        ushort4 o;
        o.x = f2bf(v.x); o.y = f2bf(v.y); o.z = f2bf(v.z); o.w = f2bf(v.w);
        Ebf4[i] = o;
    }
    if (i < N) { Z[i] = 0.0f; P[i] = 0.0f; }
}

// ---------------- kernel 2: symmetric fused sim + exp-sum + masked dot-sum ----------------
// 1024 persistent blocks x 128 thr (2 waves). Each block: contiguous chunk of the
// 8320 triangular (128-row x 32-col) tiles. Wave w owns rows rb*128 + w*64 .. +64
// (rg=4 x 16), A-frags in registers (reused until rb changes). B tile (32 cols x
// 256 k bf16, 16 KB) double-buffered in LDS via global_load_lds(16B), XOR-swizzled
// via pre-swizzled global source (linear LDS dest, rule #21).
__global__ __launch_bounds__(TPB, 2)
void sim_kernel(const __hip_bfloat16* __restrict__ Ebf,
                const int* __restrict__ labels,
                float* __restrict__ Z, float* __restrict__ P) {
    __shared__ unsigned char Bsh[2 * 16384];

    const int tid  = threadIdx.x;
    const int lane = tid & 63;
    const int w    = tid >> 6;      // wave 0..1
    const int bid  = blockIdx.x;

    const int k0 = (int)(((long long)bid * NTILES) / GRID);
    const int k1 = (int)(((long long)(bid + 1) * NTILES) / GRID);

    const char* eb = (const char*)Ebf;

    bf16x8 a[4][8];                  // A fragments: 64 rows x 256 k
    int labP[4];                     // packed labels of this lane's 16 C/D rows
    float zacc[4][4], pacc[4][4];    // per-row running sums
    int prev_rb = -1;
    int cur = 0;

    // stage a tile (32 cols x 256 k = 16 KB) into buffer `buf`
    auto stage = [&](int buf, int ct) {
#pragma unroll
        for (int m = 0; m < 8; ++m) {
            int c = w * 8 + m;                       // chunk 0..15 (1 KB each)
            int kg = c >> 1, colblk = c & 1;
            unsigned dbase = (unsigned)buf * 16384u + kg * 2048u + colblk * 1024u;
            int colLocal = colblk * 16 + (lane >> 2);
            int seg = (lane & 3) ^ ((colLocal >> 1) & 3);   // inverse swizzle on source
            const char* src = eb + (size_t)(ct * CTW + colLocal) * 512 + kg * 64 + seg * 16;
            __builtin_amdgcn_global_load_lds(
                (const __attribute__((address_space(1))) void*)src,
                (__attribute__((address_space(3))) void*)(Bsh + dbase), 16, 0, 0);
        }
    };

    // flush per-row state for row-block rb (16-lane shfl reduce + 1 atomic/row)
    auto flush_rows = [&](int rb) {
#pragma unroll
        for (int rg = 0; rg < 4; ++rg)
#pragma unroll
            for (int r = 0; r < 4; ++r) {
                float z = zacc[rg][r], p = pacc[rg][r];
#pragma unroll
                for (int m = 1; m <= 8; m <<= 1) {
                    z += __shfl_xor(z, m, 64);
                    p += __shfl_xor(p, m, 64);
                }
                if ((lane & 15) == 0) {
                    int row = rb * RB + w * 64 + rg * 16 + (lane >> 4) * 4 + r;
                    atomicAdd(&Z[row], z);
                    atomicAdd(&P[row], p);
                }
            }
    };

    // prologue: stage first tile
    {
        int rb0, ct0;
        decode_tile(k0, rb0, ct0);
        stage(0, ct0);
    }
    __syncthreads();

    for (int k = k0; k < k1; ++k) {
        int rb, ct;
        decode_tile(k, rb, ct);

        if (rb != prev_rb) {
            if (prev_rb >= 0) flush_rows(prev_rb);
#pragma unroll
            for (int rg = 0; rg < 4; ++rg) {
                int arow = rb * RB + w * 64 + rg * 16 + (lane & 15);
                const char* rp = eb + (size_t)arow * 512 + ((lane >> 4) * 16);
#pragma unroll
                for (int kg = 0; kg < 8; ++kg)
                    a[rg][kg] = *reinterpret_cast<const bf16x8*>(rp + kg * 64);
                int rr = rb * RB + w * 64 + rg * 16 + (lane >> 4) * 4;
                labP[rg] = labels[rr] | (labels[rr + 1] << 8) |
                           (labels[rr + 2] << 16) | (labels[rr + 3] << 24);
                for (int r = 0; r < 4; ++r) { zacc[rg][r] = 0.0f; pacc[rg][r] = 0.0f; }
            }
            prev_rb = rb;
        }

        // issue next tile's staging (into other buffer) before compute
        if (k + 1 < k1) {
            int rbn, ctn;
            decode_tile(k + 1, rbn, ctn);
            stage(cur ^ 1, ctn);
        }

        // column labels for this tile (L1-resident)
        int labj[2];
#pragma unroll
        for (int cg = 0; cg < 2; ++cg)
            labj[cg] = labels[ct * CTW + cg * 16 + (lane & 15)];

        // swizzled LDS read bases
        unsigned rbase[2];
#pragma unroll
        for (int cg = 0; cg < 2; ++cg) {
            unsigned col = cg * 16 + (lane & 15);
            rbase[cg] = (unsigned)cur * 16384u + col * 64u
                      + ((((unsigned)(lane >> 4)) ^ ((col >> 1) & 3u)) << 4);
        }

        f32x4 acc[4][2];
#pragma unroll
        for (int rg = 0; rg < 4; ++rg)
#pragma unroll
            for (int cg = 0; cg < 2; ++cg) acc[rg][cg] = (f32x4){0.f, 0.f, 0.f, 0.f};

#pragma unroll
        for (int kg = 0; kg < 8; ++kg) {
            bf16x8 b0 = *reinterpret_cast<const bf16x8*>(Bsh + rbase[0] + kg * 2048);
            bf16x8 b1 = *reinterpret_cast<const bf16x8*>(Bsh + rbase[1] + kg * 2048);
#pragma unroll
            for (int rg = 0; rg < 4; ++rg) {
                acc[rg][0] = __builtin_amdgcn_mfma_f32_16x16x32_bf16(a[rg][kg], b0, acc[rg][0], 0, 0, 0);
                acc[rg][1] = __builtin_amdgcn_mfma_f32_16x16x32_bf16(a[rg][kg], b1, acc[rg][1], 0, 0, 0);
            }
        }

        // epilogue: row sums always; col partials for off-diag tiles
        const bool colpath = (ct >= rb * 4 + 4);
        float zc[2] = {0.f, 0.f}, pc[2] = {0.f, 0.f};
#pragma unroll
        for (int cg = 0; cg < 2; ++cg)
#pragma unroll
            for (int rg = 0; rg < 4; ++rg)
#pragma unroll
                for (int r = 0; r < 4; ++r) {
                    float d = acc[rg][cg][r];
                    float e = fast_exp2(__builtin_fmaf(d, K1, K2));
                    zacc[rg][r] += e;
                    int lr = (labP[rg] >> (r * 8)) & 255;
                    float t = (lr == labj[cg]) ? d : 0.0f;
                    pacc[rg][r] += t;
                    zc[cg] += e;
                    pc[cg] += t;
                }

        if (colpath) {
#pragma unroll
            for (int cg = 0; cg < 2; ++cg) {
                float z = zc[cg], p = pc[cg];
                z += __shfl_xor(z, 16, 64); z += __shfl_xor(z, 32, 64);
                p += __shfl_xor(p, 16, 64); p += __shfl_xor(p, 32, 64);
                if (lane < 16) {
                    int col = ct * CTW + cg * 16 + lane;
                    atomicAdd(&Z[col], z);
                    atomicAdd(&P[col], p);
                }
            }
        }

        __syncthreads();   // drains vmcnt -> next tile staged; all reads of cur done
        cur ^= 1;
    }
    if (prev_rb >= 0) flush_rows(prev_rb);
}

// ---------------- kernel 3: finalize (hist + per-row + reduce + divide) ----------------
__global__ __launch_bounds__(1024)
void finalize_kernel(const float* __restrict__ Z, const float* __restrict__ P,
                     const int* __restrict__ labels, float* __restrict__ out) {
    __shared__ int hist[64];
    __shared__ float s0[1024], s1[1024];
    int t = threadIdx.x;
    if (t < 64) hist[t] = 0;
    __syncthreads();
    for (int i = t; i < N; i += 1024) atomicAdd(&hist[labels[i]], 1);
    __syncthreads();
    float num = 0.0f, den = 0.0f;
    for (int i = t; i < N; i += 1024) {
        float z = Z[i] - 1.0f;            // remove diag exp(s_ii-2) ~= 1
        float p = 2.0f * (P[i] - 1.0f);   // scale raw dots by T-inv=2; remove diag dot ~= 1
        float c = (float)(hist[labels[i]] - 1);
        num += c * (2.0f + __logf(z)) - p;
        den += c;
    }
    s0[t] = num; s1[t] = den;
    __syncthreads();
    for (int s = 512; s > 0; s >>= 1) {
        if (t < s) { s0[t] += s0[t + s]; s1[t] += s1[t + s]; }
        __syncthreads();
    }
    if (t == 0) out[0] = s0[0] / s1[0];
}

extern "C" void kernel_launch(void* const* d_in, const int* in_sizes, int n_in,
                              void* d_out, int out_size, void* d_ws, size_t ws_size,
                              hipStream_t stream) {
    const float* emb  = (const float*)d_in[0];
    const int* labels = (const int*)d_in[1];
    float* out = (float*)d_out;

    char* ws = (char*)d_ws;
    __hip_bfloat16* Ebf = (__hip_bfloat16*)ws;          // 4 MB
    float* Z = (float*)(ws + (size_t)N * D * 2);        // 32 KB
    float* P = Z + N;                                   // 32 KB

    convert_kernel<<<(N * D / 4 + 255) / 256, 256, 0, stream>>>(
        (const float4*)emb, (ushort4*)Ebf, Z, P);
    sim_kernel<<<GRID, TPB, 0, stream>>>(Ebf, labels, Z, P);
    finalize_kernel<<<1, 1024, 0, stream>>>(Z, P, labels, out);
}